// Round 12
// baseline (401.593 us; speedup 1.0000x reference)
//
#include <hip/hip_runtime.h>

#define NPTS   8192
#define CCH    32
#define LDIM   64
#define ODIM   128
#define KNN    16
#define QPB    64                  // queries per scan block (4 waves x 16)
#define NCHK   4                   // candidate chunks per batch
#define NTILB  128                 // 64-cand tiles per batch
#define NTILC  32                  // tiles per chunk
#define TREC   4352                // tile record: 4096B fp16 frags + 256B sq[col][st]
#define SCAPC  50                  // survivor cap/query/chunk (verified R10/R11); u16 word-stride 25 odd
#define SKSTR  51                  // skeys row stride (odd -> conflict-free)
#define MARGIN 0.75f               // >= 2*eps bound for fp16 distance error

typedef _Float16 half8   __attribute__((ext_vector_type(8)));
typedef float    float4v __attribute__((ext_vector_type(4)));

// R9/R10/R11 A/B/C: drain-barrier 190us == counted-vmcnt 208 == barrier-free
// 273 -> sync policy is NOT the bottleneck; per-wave latency exposure is.
// This round combines the two measured winners:
//   * R8's register-direct scan loop (global->VGPR, 4-tile ILP window, no LDS
//     staging, no barriers, measured 84-VGPR codegen) -- deep per-wave ILP;
//   * R9's candidate split (512 qgroups x 4 chunks = 2048 blocks -> ~6
//     blocks/CU at the 84-VGPR rung = 24 waves/CU, 3x R8's residency) -- TLP.
// Chunk-major block order: all XCDs hold the same 139KB chunk in L2 at once.
// Keys via prescaled A (-2, exact) + MFMA C preloaded with sq[cand] (verified
// R10/R11). Chunk threshold = 16-col x top-2 rank (verified); chunk-exact
// top-16 (key,idx) -> finish kernel (verbatim R10/R11, verified).
//
// scan LDS (19968 B): t32 overlay @0 (64*33*4=8448) | skeys overlay @0
//   (64*51*4=13056) | slist u16 @13056 (6400) | scnt @19456 (256) | tq @19712 (256)
#define LDSA 19968
#define A_SL 13056
#define A_SC 19456
#define A_TQ 19712

// Prologue: fp32 squared norms (same summation order -> identical bits) and
// fp16 candidates written ONCE per 64-cand tile record (R8-verified layout):
//   point p: tile=p>>6, st=(p>>4)&3, col=p&15; chan c=q*8+j ->
//   rec + st*1024 + q*256 + col*16 + j*2 ; sq at rec + 4096 + col*16 + st*4
__global__ void prep_kernel(const float* __restrict__ x, float* __restrict__ sqg,
                            char* __restrict__ xh2) {
    int p = blockIdx.x * 256 + threadIdx.x;      // 0..32767
    const float4* src = (const float4*)(x + (size_t)p * CCH);
    float4 f[8];
    #pragma unroll
    for (int k = 0; k < 8; ++k) f[k] = src[k];
    float s = 0.f;
    #pragma unroll
    for (int k = 0; k < 8; ++k)
        s += f[k].x * f[k].x + f[k].y * f[k].y + f[k].z * f[k].z + f[k].w * f[k].w;
    sqg[p] = s;
    int b = p >> 13, pp = p & (NPTS - 1);
    char* rec = xh2 + (size_t)b * NTILB * TREC + (size_t)(pp >> 6) * TREC;
    int st = (pp >> 4) & 3, col = pp & 15;
    char* fd = rec + st * 1024 + col * 16;
    #pragma unroll
    for (int q = 0; q < 4; ++q) {
        float4 a = f[2 * q], c = f[2 * q + 1];
        half8 h;
        h[0] = (_Float16)a.x; h[1] = (_Float16)a.y; h[2] = (_Float16)a.z; h[3] = (_Float16)a.w;
        h[4] = (_Float16)c.x; h[5] = (_Float16)c.y; h[6] = (_Float16)c.z; h[7] = (_Float16)c.w;
        *(half8*)(fd + q * 256) = h;
    }
    *(float*)(rec + 4096 + col * 16 + st * 4) = s;
}

__global__ __launch_bounds__(256, 2)
void scan_kernel(const float* __restrict__ x,
                 const float* __restrict__ sqg,
                 const char* __restrict__ xh2,
                 float* __restrict__ kbuf,
                 unsigned short* __restrict__ ibuf)
{
    __shared__ __align__(16) char smem[LDSA];
    float*          t32   = (float*)smem;                       // overlay
    float*          skeys = (float*)smem;                       // overlay
    unsigned short* slist = (unsigned short*)(smem + A_SL);
    int*            scnt  = (int*)(smem + A_SC);
    float*          tq    = (float*)(smem + A_TQ);

    const int tid  = threadIdx.x;
    const int lane = tid & 63;
    const int w    = tid >> 6;                 // 0..3
    const int col  = lane & 15;
    const int quad = lane >> 4;
    const float INF = __builtin_inff();

    const int chunk = blockIdx.x >> 9;         // chunk-major: L2-friendly
    const int qgi   = blockIdx.x & 511;
    const int qb0   = qgi * QPB;
    const int b     = qb0 >> 13;
    const int qbl   = qb0 & (NPTS - 1);
    const int S     = qgi & (NTILC - 1);       // tile-order stagger
    const float* xb  = x   + (size_t)(b << 13) * CCH;
    const float* sqb = sqg + (b << 13);
    const char*  xhb = xh2 + (size_t)b * NTILB * TREC;
    const int ct0   = chunk * NTILC;           // first tile of this chunk

    // ---- A-fragment prescaled by -2 (exact): MFMA(C=sq[c]) output IS the key
    half8 qh;
    {
        int pp = qbl + w * 16 + col;
        qh = *(const half8*)(xhb + (size_t)(pp >> 6) * TREC
                             + ((pp >> 4) & 3) * 1024 + quad * 256 + (pp & 15) * 16);
        #pragma unroll
        for (int i = 0; i < 8; ++i) qh[i] = qh[i] * (_Float16)-2.0f;
    }

    const char* lbase = xhb + (size_t)ct0 * TREC + (size_t)lane * 16;
    const char* sbase = xhb + (size_t)ct0 * TREC + 4096 + (size_t)col * 16;

    half8 f0[4], f1[4], f2[4], f3[4];
    float4v s0v, s1v, s2v, s3v;

#define LDSET(F, SV, T) { \
        int _t = ((T) + S) & (NTILC - 1); \
        const char* _r = lbase + (size_t)_t * TREC; \
        F[0] = *(const half8*)(_r); \
        F[1] = *(const half8*)(_r + 1024); \
        F[2] = *(const half8*)(_r + 2048); \
        F[3] = *(const half8*)(_r + 3072); \
        SV = *(const float4v*)(sbase + (size_t)_t * TREC); \
    }

    // ================= PASS 1: branch-free per-lane top-2 per query ==========
    float m1[4] = {INF, INF, INF, INF};
    float m2[4] = {INF, INF, INF, INF};

#define PASS1(F, SV) { \
        _Pragma("unroll") \
        for (int st = 0; st < 4; ++st) { \
            float sc = SV[st]; \
            float4v acc = __builtin_amdgcn_mfma_f32_16x16x32_f16( \
                qh, F[st], (float4v){sc, sc, sc, sc}, 0, 0, 0); \
            _Pragma("unroll") \
            for (int j = 0; j < 4; ++j) { \
                float key = acc[j]; \
                float o1  = m1[j]; \
                m1[j] = fminf(key, o1); \
                m2[j] = __builtin_amdgcn_fmed3f(key, o1, m2[j]); \
            } \
        } \
    }

    LDSET(f0, s0v, 0) LDSET(f1, s1v, 1) LDSET(f2, s2v, 2) LDSET(f3, s3v, 3)
    #pragma unroll 1
    for (int T = 0; T < NTILC; T += 4) {
        PASS1(f0, s0v) LDSET(f0, s0v, T + 4)   // tail loads wrap: harmless
        PASS1(f1, s1v) LDSET(f1, s1v, T + 5)
        PASS1(f2, s2v) LDSET(f2, s2v, T + 6)
        PASS1(f3, s3v) LDSET(f3, s3v, T + 7)
    }

    // ---- chunk threshold: 16th smallest of 16-col x top-2 = 32 values ----
    #pragma unroll
    for (int j = 0; j < 4; ++j) {
        int qq = w * 16 + quad * 4 + j;
        t32[qq * 33 + col * 2 + 0] = m1[j];
        t32[qq * 33 + col * 2 + 1] = m2[j];
    }
    __syncthreads();
    {
        int q = tid & 63, wt = tid >> 6;       // 4 workers x 8 items
        float v[8]; int r[8];
        #pragma unroll
        for (int u = 0; u < 8; ++u) { v[u] = t32[q * 33 + wt * 8 + u]; r[u] = 0; }
        #pragma unroll 8
        for (int jj = 0; jj < 32; ++jj) {
            float vj = t32[q * 33 + jj];
            #pragma unroll
            for (int u = 0; u < 8; ++u)
                r[u] += (int)(vj < v[u]) | ((int)(vj == v[u]) & (int)(jj < wt * 8 + u));
        }
        #pragma unroll
        for (int u = 0; u < 8; ++u)
            if (r[u] == KNN - 1) tq[q] = v[u];
        if (tid < QPB) scnt[tid] = 0;
    }
    __syncthreads();
    float T2[4];
    #pragma unroll
    for (int j = 0; j < 4; ++j) T2[j] = tq[w * 16 + quad * 4 + j] + MARGIN;

    // ================= PASS 2: rescan, atomic survivor append ==========
#define PASS2(F, SV, T) { \
        int _tb = (ct0 + (((T) + S) & (NTILC - 1))) * 64; \
        _Pragma("unroll") \
        for (int st = 0; st < 4; ++st) { \
            float sc = SV[st]; \
            float4v acc = __builtin_amdgcn_mfma_f32_16x16x32_f16( \
                qh, F[st], (float4v){sc, sc, sc, sc}, 0, 0, 0); \
            _Pragma("unroll") \
            for (int j = 0; j < 4; ++j) { \
                float key = acc[j]; \
                if (key < T2[j]) { \
                    int qq = w * 16 + quad * 4 + j; \
                    int slot = atomicAdd(&scnt[qq], 1); \
                    if (slot < SCAPC) \
                        slist[qq * SCAPC + slot] = \
                            (unsigned short)(_tb + st * 16 + col); \
                } \
            } \
        } \
    }

    LDSET(f0, s0v, 0) LDSET(f1, s1v, 1) LDSET(f2, s2v, 2) LDSET(f3, s3v, 3)
    #pragma unroll 1
    for (int T = 0; T < NTILC; T += 4) {
        PASS2(f0, s0v, T)     LDSET(f0, s0v, T + 4)
        PASS2(f1, s1v, T + 1) LDSET(f1, s1v, T + 5)
        PASS2(f2, s2v, T + 2) LDSET(f2, s2v, T + 6)
        PASS2(f3, s3v, T + 3) LDSET(f3, s3v, T + 7)
    }
    __syncthreads();

    // ================= PASS 3: exact fp32 re-check of survivors ==========
    {
        int qq = tid & 63, sb4 = tid >> 6;     // 4 workers per query
        int n = scnt[qq]; if (n > SCAPC) n = SCAPC;
        const float4* xi4 = (const float4*)(xb + (size_t)(qbl + qq) * CCH);
        for (int s = sb4; s < n; s += 4) {
            int jdx = slist[qq * SCAPC + s];
            const float4* xj = (const float4*)(xb + (size_t)jdx * CCH);
            float a0 = 0.f, a1 = 0.f, a2 = 0.f, a3 = 0.f;
            #pragma unroll 2
            for (int k = 0; k < 8; ++k) {
                float4 cv = xj[k], qv = xi4[k];
                a0 = fmaf(cv.x, qv.x, a0); a1 = fmaf(cv.y, qv.y, a1);
                a2 = fmaf(cv.z, qv.z, a2); a3 = fmaf(cv.w, qv.w, a3);
            }
            float dot = (a0 + a1) + (a2 + a3);
            skeys[qq * SKSTR + s] = fmaf(-2.f, dot, sqb[jdx]);
        }
    }
    __syncthreads();
    // ===== chunk-exact top-16 via rank (lex on (key, idx)) -> (key f32, idx u16)
    {
        int q = tid & 63, wt = tid >> 6;
        int n = scnt[q]; if (n > SCAPC) n = SCAPC;
        float*          kdst = kbuf + (size_t)(qb0 + q) * 64 + chunk * KNN;
        unsigned short* idst = ibuf + (size_t)(qb0 + q) * 64 + chunk * KNN;
        for (int s = wt; s < n; s += 4) {
            float k = skeys[q * SKSTR + s];
            int   i = slist[q * SCAPC + s];
            int rank = 0;
            #pragma unroll 4
            for (int jj = 0; jj < n; ++jj) {
                float kj = skeys[q * SKSTR + jj];
                int   ij = slist[q * SCAPC + jj];
                rank += (int)(kj < k) | ((int)(kj == k) & (int)(ij < i));
            }
            if (rank < KNN) { kdst[rank] = k; idst[rank] = (unsigned short)i; }
        }
    }
}

// finish: 32 q/block, 1024 blocks. Merge 4x16 precomputed exact (key,idx) by
// lex rank (chunks disjoint -> unique idx), then verified epilogue. (R10 verbatim)
#define LDSB 14976
__global__ __launch_bounds__(256, 4)
void finish_kernel(const float* __restrict__ x,
                   const float* __restrict__ kbuf,
                   const unsigned short* __restrict__ ibuf,
                   const float* __restrict__ Wl,
                   const float* __restrict__ bl,
                   const float* __restrict__ Wc,
                   const float* __restrict__ bc,
                   float* __restrict__ out)
{
    __shared__ __align__(16) char smem[LDSB];
    float*          mkeys = (float*)smem;
    unsigned short* midx  = (unsigned short*)(smem + 8320);
    int*            kn    = (int*)(smem + 12928);
    float*          pl    = (float*)smem;          // epilogue overlays
    float*          hh    = (float*)(smem + 4224);

    const int tid = threadIdx.x;
    const int b   = blockIdx.x >> 8;               // 256 qgroups per batch
    const int qbl = (blockIdx.x & 255) * 32;
    const int qb0 = (b << 13) + qbl;
    const float* xb = x + (size_t)(b << 13) * CCH;
    const float INF = __builtin_inff();

    {
        int q = tid >> 3, c8 = (tid & 7) * 8;
        const float4* ks = (const float4*)(kbuf + (size_t)(qb0 + q) * 64 + c8);
        float4 k0 = ks[0], k1 = ks[1];
        uint4 iv = *(const uint4*)(ibuf + (size_t)(qb0 + q) * 64 + c8);
        float* kd = mkeys + q * 65 + c8;
        kd[0] = k0.x; kd[1] = k0.y; kd[2] = k0.z; kd[3] = k0.w;
        kd[4] = k1.x; kd[5] = k1.y; kd[6] = k1.z; kd[7] = k1.w;
        *(uint4*)(midx + q * 72 + c8) = iv;
    }
    __syncthreads();
    {
        int q = tid >> 3, wt = tid & 7;
        for (int c = wt; c < 64; c += 8) {
            float k = mkeys[q * 65 + c];
            int   i = midx[q * 72 + c];
            int rank = 0;
            #pragma unroll 4
            for (int jj = 0; jj < 64; ++jj) {
                float kj = mkeys[q * 65 + jj];
                int   ij = midx[q * 72 + jj];
                rank += (int)(kj < k) | ((int)(kj == k) & (int)(ij < i));
            }
            if (rank < KNN) kn[q * KNN + rank] = i;
        }
    }
    __syncthreads();
    {
        int q = tid >> 3, part = tid & 7;
        float4 m0 = make_float4(-INF, -INF, -INF, -INF);
        #pragma unroll 4
        for (int k = 0; k < KNN; ++k) {
            int j = kn[q * KNN + k];
            float4 v = *(const float4*)(xb + (size_t)j * CCH + part * 4);
            m0.x = fmaxf(m0.x, v.x); m0.y = fmaxf(m0.y, v.y);
            m0.z = fmaxf(m0.z, v.z); m0.w = fmaxf(m0.w, v.w);
        }
        float* d = pl + q * 33 + part * 4;
        d[0] = m0.x; d[1] = m0.y; d[2] = m0.z; d[3] = m0.w;
    }
    __syncthreads();
    {
        int l = tid & 63, qg2 = tid >> 6;
        #pragma unroll 1
        for (int qq = qg2; qq < 32; qq += 4) {
            float acc = bl[l];
            #pragma unroll 8
            for (int c = 0; c < CCH; ++c)
                acc = fmaf(pl[qq * 33 + c], Wl[c * LDIM + l], acc);
            hh[qq * 65 + l] = acc;
        }
    }
    __syncthreads();
    {
        int o = tid & 127, qh2 = tid >> 7;
        #pragma unroll 1
        for (int qq = qh2; qq < 32; qq += 2) {
            float acc = bc[o];
            #pragma unroll 8
            for (int l = 0; l < LDIM; ++l)
                acc = fmaf(hh[qq * 65 + l], Wc[l * ODIM + o], acc);
            out[(size_t)(qb0 + qq) * ODIM + o] = fmaxf(acc, 0.f);
        }
    }
}

extern "C" void kernel_launch(void* const* d_in, const int* in_sizes, int n_in,
                              void* d_out, int out_size, void* d_ws, size_t ws_size,
                              hipStream_t stream) {
    const float* x  = (const float*)d_in[0];
    const float* Wl = (const float*)d_in[1];
    const float* bl = (const float*)d_in[2];
    const float* Wc = (const float*)d_in[3];
    const float* bc = (const float*)d_in[4];
    float* out = (float*)d_out;
    float*          sqf  = (float*)d_ws;                               // 128 KB
    char*           xh2  = (char*)d_ws + 131072;                       // 512 rec x 4352B = 2.23 MB
    float*          kbuf = (float*)((char*)d_ws + 2359296);            // 8 MB
    unsigned short* ibuf = (unsigned short*)((char*)d_ws + 10747904);  // 4 MB (total ~14.1 MB)
    (void)in_sizes; (void)n_in; (void)out_size; (void)ws_size;

    hipLaunchKernelGGL(prep_kernel, dim3((4 * NPTS) / 256), dim3(256), 0, stream,
                       x, sqf, xh2);
    hipLaunchKernelGGL(scan_kernel, dim3(512 * NCHK), dim3(256), 0, stream,
                       x, sqf, xh2, kbuf, ibuf);
    hipLaunchKernelGGL(finish_kernel, dim3(1024), dim3(256), 0, stream,
                       x, kbuf, ibuf, Wl, bl, Wc, bc, out);
}

// Round 13
// 247.505 us; speedup vs baseline: 1.6226x; 1.6226x over previous
//
#include <hip/hip_runtime.h>

#define NPTS   8192
#define CCH    32
#define LDIM   64
#define ODIM   128
#define KNN    16
#define QPB    64                  // queries per block (16 per wave = MFMA tile rows)
#define TILEC  128                 // candidates per LDS tile
#define NTIL   (NPTS / TILEC)      // 64
#define NBLK   ((4 * NPTS) / QPB)  // 512 blocks
#define SCAP   57                  // survivor capacity (worst ~40); odd stride -> conflict-free rank reads
#define MARGIN 0.75f               // >= 2*eps bound for fp16 distance error
#define T32STR 65                  // t32 row stride (odd -> conflict-free column reads)

typedef _Float16 half8   __attribute__((ext_vector_type(8)));
typedef float    float4v __attribute__((ext_vector_type(4)));

// CHAMPION (Round-5 kernel, measured 195us dispatch / 241us bench) + ONE
// verified micro-opt. R7-R12 falsified every structural alternative (fat
// blocks 289, reg-scan 238, chunk-split 331, counted-vmcnt 313, barrier-free
// 382, ILP+TLP 401) -> fall back to champion per pre-commit.
// Micro-opt (verified exact in R8/R10/R11/R12, all absmax 0): A-fragment
// prescaled by -2 (binade shift, exact fp16) + MFMA C preloaded with splatted
// sq[cand] -> MFMA output IS the key; deletes 32 fmaf VALU per tile-iter from
// the dominant VALU stream (VALUBusy 48%). Threshold margin unaffected
// (ulp-level key change << MARGIN; pass-3 exact recheck unchanged).
//
// 512-thread block = 8 waves = 2 wave-groups; group g scans tiles of parity g
// with its own double-buffer pair. Tile order staggered by blockIdx.
// __launch_bounds__(512,4) -> 64-VGPR budget -> 8 waves/SIMD eligibility,
// residency 2 blocks/CU = 16 waves/CU (R5/R6 evidence). Unroll limits on
// selection/epilogue phases prevent 64-reg spills (R6 evidence: VGPR=44).
//
// LDS map:
//  scan:   buf[g][p] @ (g*2+p)*8704, 4 x 8704 = 34816  (8192 xh + 512 sq each)
//          slist @34816 (64*57*4 = 14592) | scnt @49408 (256) | tq @49664 (256)
//          kn @49920 (4096)  -> total 54016
//          t32 overlay @0 (64*65*4 = 16640) after pass-1 (dead before pass-2 staging)
//  pass3:  skeys overlay @0 (14592)   (stage bufs dead)
//  epilog: pl @0 (8448) | hh @8704 (16640)   (kn alive @49920)
#define LDS_BYTES 54016
#define OFF_SQ   8192              // sq row offset inside a stage buffer
#define OFF_SL   34816
#define OFF_SC   49408
#define OFF_TQ   49664
#define OFF_KN   49920
#define OFF_HH   8704

__device__ __forceinline__ void gload_lds16(const void* g, void* l) {
    __builtin_amdgcn_global_load_lds(
        (const __attribute__((address_space(1))) unsigned int*)g,
        (__attribute__((address_space(3))) unsigned int*)l, 16, 0, 0);
}
__device__ __forceinline__ void gload_lds4(const void* g, void* l) {
    __builtin_amdgcn_global_load_lds(
        (const __attribute__((address_space(1))) unsigned int*)g,
        (__attribute__((address_space(3))) unsigned int*)l, 4, 0, 0);
}

// Prologue: fp32 squared norms (same summation order -> identical bits) and
// fp16 candidates written ONCE in B-fragment order:
//   point p, channel c=q*8+j -> half8 index (p>>7)*512 + ((p>>4)&7)*64 + (p&15), quad q stride 16
__global__ void prep_kernel(const float* __restrict__ x, float* __restrict__ sqg,
                            _Float16* __restrict__ xh) {
    int p = blockIdx.x * 256 + threadIdx.x;      // 0..32767
    const float4* src = (const float4*)(x + (size_t)p * CCH);
    float4 f[8];
    #pragma unroll
    for (int k = 0; k < 8; ++k) f[k] = src[k];
    float s = 0.f;
    #pragma unroll
    for (int k = 0; k < 8; ++k)
        s += f[k].x * f[k].x + f[k].y * f[k].y + f[k].z * f[k].z + f[k].w * f[k].w;
    sqg[p] = s;
    half8* dst = (half8*)xh + ((p >> 7) * 512 + ((p >> 4) & 7) * 64 + (p & 15));
    #pragma unroll
    for (int q = 0; q < 4; ++q) {
        float4 a = f[2 * q], c = f[2 * q + 1];
        half8 h;
        h[0] = (_Float16)a.x; h[1] = (_Float16)a.y; h[2] = (_Float16)a.z; h[3] = (_Float16)a.w;
        h[4] = (_Float16)c.x; h[5] = (_Float16)c.y; h[6] = (_Float16)c.z; h[7] = (_Float16)c.w;
        dst[q * 16] = h;                          // quad stride = 128 halfs = 16 half8
    }
}

__global__ __launch_bounds__(512, 4)
void graph_layer_kernel(const float* __restrict__ x,
                        const float* __restrict__ sqg,
                        const _Float16* __restrict__ xh,
                        const float* __restrict__ Wl,
                        const float* __restrict__ bl,
                        const float* __restrict__ Wc,
                        const float* __restrict__ bc,
                        float* __restrict__ out)
{
    __shared__ __align__(16) char smem[LDS_BYTES];
    int*   slist = (int*)(smem + OFF_SL);
    float* t32   = (float*)smem;               // overlay on stage bufs, post-pass-1
    int*   scnt  = (int*)(smem + OFF_SC);
    float* tq    = (float*)(smem + OFF_TQ);
    float* skeys = (float*)smem;               // pass-3 overlay
    int*   kn    = (int*)(smem + OFF_KN);
    float* pl    = (float*)smem;               // epilogue overlays
    float* hh    = (float*)(smem + OFF_HH);

    const int tid  = threadIdx.x;
    const int lane = tid & 63;
    const int w    = tid >> 6;                 // 0..7
    const int g    = w >> 2;                   // wave group: 0 = even tiles, 1 = odd
    const int lw   = w & 3;                    // wave within group
    const int col  = lane & 15;                // candidate column / A-frag row
    const int quad = lane >> 4;
    const float INF = __builtin_inff();

    const int qb0 = blockIdx.x * QPB;
    const int b   = qb0 >> 13;
    const int qbl = qb0 & (NPTS - 1);
    const int S   = blockIdx.x & 31;           // tile-order stagger
    const float* xb  = x   + (size_t)(b << 13) * CCH;
    const float* sqb = sqg + (b << 13);
    const char*  xhb = (const char*)xh + (size_t)b * NTIL * 8192;

    // ---- A-fragment prescaled by -2 (exact): MFMA(C=sq[c]) output IS the key
    half8 qh;
    {
        int p = qb0 + lw * 16 + col;
        qh = *(const half8*)((const char*)xh
              + (size_t)(p >> 7) * 8192 + ((p >> 4) & 7) * 1024
              + quad * 256 + (p & 15) * 16);
        #pragma unroll
        for (int i = 0; i < 8; ++i) qh[i] = qh[i] * (_Float16)-2.0f;
    }

    auto tileof = [&](int I) { return (((I + S) & 31) << 1) | g; };
    auto bufat  = [&](int I) { return smem + (((g << 1) | (I & 1)) * 8704); };

    // async stage of super-iter I's tile for this group: 8KB fp16 + 512B sq
    auto stage = [&](int I) {
        char* sb = bufat(I);
        int tile = tileof(I);
        const char* src = xhb + (size_t)tile * 8192;
        int tg = tid & 255;                     // thread index within group
        gload_lds16(src + tg * 16,        sb + lw * 1024);   // lds = base + lane*16
        gload_lds16(src + 4096 + tg * 16, sb + 4096 + lw * 1024);
        if (lw < 2)
            gload_lds4(sqb + tile * TILEC + lw * 64 + lane, sb + OFF_SQ + lw * 256);
    };

    // ================= PASS 1: branch-free per-lane top-2 per query ==========
    float m1[4] = {INF, INF, INF, INF};
    float m2[4] = {INF, INF, INF, INF};

    stage(0);
    __syncthreads();
    #pragma unroll 1
    for (int I = 0; I < 32; ++I) {
        if (I + 1 < 32) stage(I + 1);
        const char*  cb = bufat(I);
        const float* sv = (const float*)(cb + OFF_SQ);
        #pragma unroll
        for (int st = 0; st < 8; ++st) {
            half8 bh = *(const half8*)(cb + st * 1024 + lane * 16);   // conflict-free
            float sc = sv[st * 16 + col];
            float4v acc = __builtin_amdgcn_mfma_f32_16x16x32_f16(
                qh, bh, (float4v){sc, sc, sc, sc}, 0, 0, 0);
            #pragma unroll
            for (int j = 0; j < 4; ++j) {
                float key = acc[j];
                float o1  = m1[j];
                m1[j] = fminf(key, o1);
                // 2nd-smallest of {key, o1, m2} == min(m2, max(key, o1)) given o1<=m2
                m2[j] = __builtin_amdgcn_fmed3f(key, o1, m2[j]);
            }
        }
        __syncthreads();
    }

    // ---- per-query threshold: 16th smallest of the 64-value union ----
    // Rank-based (exact, lex tie-break): rank(i) = #{j : v_j < v_i or (==, j<i)}.
    #pragma unroll
    for (int j = 0; j < 4; ++j) {
        int qq = lw * 16 + quad * 4 + j;
        t32[qq * T32STR + g * 32 + col * 2 + 0] = m1[j];
        t32[qq * T32STR + g * 32 + col * 2 + 1] = m2[j];
    }
    __syncthreads();
    {
        int q  = tid & 63;                     // query
        int wt = tid >> 6;                     // worker 0..7, items wt*8..wt*8+7
        float v[8]; int r[8];
        #pragma unroll
        for (int u = 0; u < 8; ++u) { v[u] = t32[q * T32STR + wt * 8 + u]; r[u] = 0; }
        #pragma unroll 8
        for (int jj = 0; jj < 64; ++jj) {
            float vj = t32[q * T32STR + jj];   // odd stride -> 2-way max, no conflicts
            #pragma unroll
            for (int u = 0; u < 8; ++u)
                r[u] += (int)(vj < v[u]) | ((int)(vj == v[u]) & (int)(jj < wt * 8 + u));
        }
        #pragma unroll
        for (int u = 0; u < 8; ++u)
            if (r[u] == KNN - 1) tq[q] = v[u];
        if (tid < QPB) scnt[tid] = 0;
    }
    __syncthreads();
    float T2[4];
    #pragma unroll
    for (int j = 0; j < 4; ++j) T2[j] = tq[lw * 16 + quad * 4 + j] + MARGIN;

    // ================= PASS 2: rescan, atomic survivor append ==========
    stage(0);
    __syncthreads();
    #pragma unroll 1
    for (int I = 0; I < 32; ++I) {
        if (I + 1 < 32) stage(I + 1);
        const char*  cb = bufat(I);
        const float* sv = (const float*)(cb + OFF_SQ);
        int tbase = tileof(I) * TILEC;
        #pragma unroll
        for (int st = 0; st < 8; ++st) {
            half8 bh = *(const half8*)(cb + st * 1024 + lane * 16);
            float sc = sv[st * 16 + col];
            float4v acc = __builtin_amdgcn_mfma_f32_16x16x32_f16(
                qh, bh, (float4v){sc, sc, sc, sc}, 0, 0, 0);
            #pragma unroll
            for (int j = 0; j < 4; ++j) {
                float key = acc[j];
                if (key < T2[j]) {
                    int qq = lw * 16 + quad * 4 + j;
                    int slot = atomicAdd(&scnt[qq], 1);
                    if (slot < SCAP)
                        slist[qq * SCAP + slot] = tbase + st * 16 + col;
                }
            }
        }
        __syncthreads();
    }

    // ================= PASS 3: exact fp32 re-check of survivors ==========
    // unroll 2 keeps the live set ~20 regs (no spill at the 64-VGPR budget)
    {
        int qq = tid & 63, sb8 = tid >> 6;     // 8 workers per query
        int n = scnt[qq]; if (n > SCAP) n = SCAP;
        const float4* xi4 = (const float4*)(xb + (size_t)(qbl + qq) * CCH);
        for (int s = sb8; s < n; s += 8) {
            int jdx = slist[qq * SCAP + s];
            const float4* xj = (const float4*)(xb + (size_t)jdx * CCH);
            float a0 = 0.f, a1 = 0.f, a2 = 0.f, a3 = 0.f;
            #pragma unroll 2
            for (int k = 0; k < 8; ++k) {
                float4 cv = xj[k], qv = xi4[k];
                a0 = fmaf(cv.x, qv.x, a0); a1 = fmaf(cv.y, qv.y, a1);
                a2 = fmaf(cv.z, qv.z, a2); a3 = fmaf(cv.w, qv.w, a3);
            }
            float dot = (a0 + a1) + (a2 + a3);
            skeys[qq * SCAP + s] = fmaf(-2.f, dot, sqb[jdx]);
        }
    }
    __syncthreads();
    // ---- exact top-16 set via rank (lex on (key, idx)); kn order = rank.
    // n >= 16 guaranteed (threshold >= true 16th + MARGIN covers fp16 error).
    {
        int q  = tid & 63;
        int wt = tid >> 6;
        int n = scnt[q]; if (n > SCAP) n = SCAP;
        for (int s = wt; s < n; s += 8) {
            float k = skeys[q * SCAP + s];
            int   i = slist[q * SCAP + s];
            int rank = 0;
            #pragma unroll 4
            for (int jj = 0; jj < n; ++jj) {
                float kj = skeys[q * SCAP + jj];   // stride 57 -> conflict-free
                int   ij = slist[q * SCAP + jj];
                rank += (int)(kj < k) | ((int)(kj == k) & (int)(ij < i));
            }
            if (rank < KNN) kn[q * KNN + rank] = i;
        }
    }
    __syncthreads();

    // ================= epilogue: gather + max-pool + MLP ==========
    {
        int q = tid >> 3, part = tid & 7;      // 8 threads/query, one float4 each
        float4 m0 = make_float4(-INF, -INF, -INF, -INF);
        #pragma unroll 4
        for (int k = 0; k < KNN; ++k) {
            int j = kn[q * KNN + k];
            float4 v = *(const float4*)(xb + (size_t)j * CCH + part * 4);
            m0.x = fmaxf(m0.x, v.x); m0.y = fmaxf(m0.y, v.y);
            m0.z = fmaxf(m0.z, v.z); m0.w = fmaxf(m0.w, v.w);
        }
        float* d = pl + q * 33 + part * 4;
        d[0] = m0.x; d[1] = m0.y; d[2] = m0.z; d[3] = m0.w;
    }
    __syncthreads();
    {
        int l = tid & 63, qg2 = tid >> 6;      // 8 query-slices
        #pragma unroll 1
        for (int qq = qg2; qq < QPB; qq += 8) {
            float acc = bl[l];
            #pragma unroll 8
            for (int c = 0; c < CCH; ++c)
                acc = fmaf(pl[qq * 33 + c], Wl[c * LDIM + l], acc);
            hh[qq * 65 + l] = acc;
        }
    }
    __syncthreads();
    {
        int o = tid & 127, qh2 = tid >> 7;     // 4 query-slices
        #pragma unroll 1
        for (int qq = qh2; qq < QPB; qq += 4) {
            float acc = bc[o];
            #pragma unroll 8
            for (int l = 0; l < LDIM; ++l)
                acc = fmaf(hh[qq * 65 + l], Wc[l * ODIM + o], acc);
            out[(size_t)(qb0 + qq) * ODIM + o] = fmaxf(acc, 0.f);
        }
    }
}

extern "C" void kernel_launch(void* const* d_in, const int* in_sizes, int n_in,
                              void* d_out, int out_size, void* d_ws, size_t ws_size,
                              hipStream_t stream) {
    const float* x  = (const float*)d_in[0];
    const float* Wl = (const float*)d_in[1];
    const float* bl = (const float*)d_in[2];
    const float* Wc = (const float*)d_in[3];
    const float* bc = (const float*)d_in[4];
    float* out = (float*)d_out;
    float*    sqf = (float*)d_ws;                       // 32768 fp32 = 128 KB
    _Float16* xh  = (_Float16*)((char*)d_ws + 131072);  // 32768 x 32 fp16 = 2 MB, frag-order
    (void)in_sizes; (void)n_in; (void)out_size; (void)ws_size;

    hipLaunchKernelGGL(prep_kernel, dim3((4 * NPTS) / 256), dim3(256), 0, stream, x, sqf, xh);
    hipLaunchKernelGGL(graph_layer_kernel, dim3(NBLK), dim3(512), 0, stream,
                       x, sqf, xh, Wl, bl, Wc, bc, out);
}

// Round 15
// 235.738 us; speedup vs baseline: 1.7036x; 1.0499x over previous
//
#include <hip/hip_runtime.h>

#define NPTS   8192
#define CCH    32
#define LDIM   64
#define ODIM   128
#define KNN    16
#define QPB    64                  // queries per block (16 per wave = MFMA tile rows)
#define TILEC  128                 // candidates per LDS tile
#define NTIL   (NPTS / TILEC)      // 64
#define NBLK   ((4 * NPTS) / QPB)  // 512 blocks
#define SCAP   57                  // survivor capacity (worst ~40); odd stride -> conflict-free rank reads
#define MARGIN 0.75f               // >= 2*eps bound for fp16 distance error
#define T32STR 65                  // t32 row stride (odd -> conflict-free column reads)

typedef _Float16 half8   __attribute__((ext_vector_type(8)));
typedef float    float4v __attribute__((ext_vector_type(4)));

// CHAMPION (R6 kernel: 195us dispatch / 241us bench, VGPR 44) + ONE change:
// XCD-aware block swizzle (T1). R13 showed C-preload regresses (-4%: splat
// movs replace fmaf 1:1 AND put the sv read on the MFMA input dep chain) ->
// reverted to the R6 fmaf form.
// Swizzle rationale: all 512 blocks stream a per-batch 2.1MB xh region, but
// default dispatch round-robins blocks across 8 XCDs -> each 4MB L2 sees all
// 4 batches (8.5MB) and thrashes (FETCH_SIZE 20.4MB ~ 10x the workspace).
// Remap so XCD k serves only batch k>>1: vb = (xcd>>1)*128 + (xcd&1)*64 + (bid>>3)
// (bijective on [0,512)) -> per-XCD scan working set = 2.1MB + sq, L2-resident.
// Blocks are fully independent -> any bijection is correctness-neutral.
//
// 512-thread block = 8 waves = 2 wave-groups; group g scans tiles of parity g
// with its own double-buffer pair. __launch_bounds__(512,4) -> 64-VGPR budget
// -> 8 waves/SIMD eligibility, 2 blocks/CU = 16 waves/CU (R5/R6 evidence).
// Unroll limits on selection/epilogue prevent 64-reg spills (R6: VGPR=44).
//
// LDS map:
//  scan:   buf[g][p] @ (g*2+p)*8704, 4 x 8704 = 34816  (8192 xh + 512 sq each)
//          slist @34816 (64*57*4 = 14592) | scnt @49408 (256) | tq @49664 (256)
//          kn @49920 (4096)  -> total 54016
//          t32 overlay @0 (64*65*4 = 16640) after pass-1 (dead before pass-2 staging)
//  pass3:  skeys overlay @0 (14592)   (stage bufs dead)
//  epilog: pl @0 (8448) | hh @8704 (16640)   (kn alive @49920)
#define LDS_BYTES 54016
#define OFF_SQ   8192              // sq row offset inside a stage buffer
#define OFF_SL   34816
#define OFF_SC   49408
#define OFF_TQ   49664
#define OFF_KN   49920
#define OFF_HH   8704

__device__ __forceinline__ void gload_lds16(const void* g, void* l) {
    __builtin_amdgcn_global_load_lds(
        (const __attribute__((address_space(1))) unsigned int*)g,
        (__attribute__((address_space(3))) unsigned int*)l, 16, 0, 0);
}
__device__ __forceinline__ void gload_lds4(const void* g, void* l) {
    __builtin_amdgcn_global_load_lds(
        (const __attribute__((address_space(1))) unsigned int*)g,
        (__attribute__((address_space(3))) unsigned int*)l, 4, 0, 0);
}

// Prologue: fp32 squared norms (same summation order -> identical bits) and
// fp16 candidates written ONCE in B-fragment order:
//   point p, channel c=q*8+j -> half8 index (p>>7)*512 + ((p>>4)&7)*64 + (p&15), quad q stride 16
__global__ void prep_kernel(const float* __restrict__ x, float* __restrict__ sqg,
                            _Float16* __restrict__ xh) {
    int p = blockIdx.x * 256 + threadIdx.x;      // 0..32767
    const float4* src = (const float4*)(x + (size_t)p * CCH);
    float4 f[8];
    #pragma unroll
    for (int k = 0; k < 8; ++k) f[k] = src[k];
    float s = 0.f;
    #pragma unroll
    for (int k = 0; k < 8; ++k)
        s += f[k].x * f[k].x + f[k].y * f[k].y + f[k].z * f[k].z + f[k].w * f[k].w;
    sqg[p] = s;
    half8* dst = (half8*)xh + ((p >> 7) * 512 + ((p >> 4) & 7) * 64 + (p & 15));
    #pragma unroll
    for (int q = 0; q < 4; ++q) {
        float4 a = f[2 * q], c = f[2 * q + 1];
        half8 h;
        h[0] = (_Float16)a.x; h[1] = (_Float16)a.y; h[2] = (_Float16)a.z; h[3] = (_Float16)a.w;
        h[4] = (_Float16)c.x; h[5] = (_Float16)c.y; h[6] = (_Float16)c.z; h[7] = (_Float16)c.w;
        dst[q * 16] = h;                          // quad stride = 128 halfs = 16 half8
    }
}

__global__ __launch_bounds__(512, 4)
void graph_layer_kernel(const float* __restrict__ x,
                        const float* __restrict__ sqg,
                        const _Float16* __restrict__ xh,
                        const float* __restrict__ Wl,
                        const float* __restrict__ bl,
                        const float* __restrict__ Wc,
                        const float* __restrict__ bc,
                        float* __restrict__ out)
{
    __shared__ __align__(16) char smem[LDS_BYTES];
    int*   slist = (int*)(smem + OFF_SL);
    float* t32   = (float*)smem;               // overlay on stage bufs, post-pass-1
    int*   scnt  = (int*)(smem + OFF_SC);
    float* tq    = (float*)(smem + OFF_TQ);
    float* skeys = (float*)smem;               // pass-3 overlay
    int*   kn    = (int*)(smem + OFF_KN);
    float* pl    = (float*)smem;               // epilogue overlays
    float* hh    = (float*)(smem + OFF_HH);

    const int tid  = threadIdx.x;
    const int lane = tid & 63;
    const int w    = tid >> 6;                 // 0..7
    const int g    = w >> 2;                   // wave group: 0 = even tiles, 1 = odd
    const int lw   = w & 3;                    // wave within group
    const int col  = lane & 15;                // candidate column / A-frag row
    const int quad = lane >> 4;
    const float INF = __builtin_inff();

    // XCD-aware swizzle: dispatch XCD = bid%8 (round-robin). Map so each XCD
    // serves ONE batch -> its L2 holds just that batch's 2.1MB xh. Bijective.
    const int bid = blockIdx.x;
    const int xcd = bid & 7, ixc = bid >> 3;   // ixc in [0,64)
    const int vb  = ((xcd >> 1) << 7) | ((xcd & 1) << 6) | ixc;

    const int qb0 = vb * QPB;
    const int b   = qb0 >> 13;
    const int qbl = qb0 & (NPTS - 1);
    const int S   = vb & 31;                   // tile-order stagger
    const float* xb  = x   + (size_t)(b << 13) * CCH;
    const float* sqb = sqg + (b << 13);
    const char*  xhb = (const char*)xh + (size_t)b * NTIL * 8192;

    // ---- A-fragment from fp16 workspace: A[m=col][k=quad*8+j], queries lw*16+col
    half8 qh;
    {
        int p = qb0 + lw * 16 + col;
        qh = *(const half8*)((const char*)xh
              + (size_t)(p >> 7) * 8192 + ((p >> 4) & 7) * 1024
              + quad * 256 + (p & 15) * 16);
    }

    auto tileof = [&](int I) { return (((I + S) & 31) << 1) | g; };
    auto bufat  = [&](int I) { return smem + (((g << 1) | (I & 1)) * 8704); };

    // async stage of super-iter I's tile for this group: 8KB fp16 + 512B sq
    auto stage = [&](int I) {
        char* sb = bufat(I);
        int tile = tileof(I);
        const char* src = xhb + (size_t)tile * 8192;
        int tg = tid & 255;                     // thread index within group
        gload_lds16(src + tg * 16,        sb + lw * 1024);   // lds = base + lane*16
        gload_lds16(src + 4096 + tg * 16, sb + 4096 + lw * 1024);
        if (lw < 2)
            gload_lds4(sqb + tile * TILEC + lw * 64 + lane, sb + OFF_SQ + lw * 256);
    };

    // ================= PASS 1: branch-free per-lane top-2 per query ==========
    float m1[4] = {INF, INF, INF, INF};
    float m2[4] = {INF, INF, INF, INF};

    stage(0);
    __syncthreads();
    #pragma unroll 1
    for (int I = 0; I < 32; ++I) {
        if (I + 1 < 32) stage(I + 1);
        const char*  cb = bufat(I);
        const float* sv = (const float*)(cb + OFF_SQ);
        #pragma unroll
        for (int st = 0; st < 8; ++st) {
            half8 bh = *(const half8*)(cb + st * 1024 + lane * 16);   // conflict-free
            float sc = sv[st * 16 + col];
            float4v acc = __builtin_amdgcn_mfma_f32_16x16x32_f16(
                qh, bh, (float4v){0.f, 0.f, 0.f, 0.f}, 0, 0, 0);
            #pragma unroll
            for (int j = 0; j < 4; ++j) {
                float key = fmaf(-2.f, acc[j], sc);
                float o1  = m1[j];
                m1[j] = fminf(key, o1);
                // 2nd-smallest of {key, o1, m2} == min(m2, max(key, o1)) given o1<=m2
                m2[j] = __builtin_amdgcn_fmed3f(key, o1, m2[j]);
            }
        }
        __syncthreads();
    }

    // ---- per-query threshold: 16th smallest of the 64-value union ----
    // Rank-based (exact, lex tie-break): rank(i) = #{j : v_j < v_i or (==, j<i)}.
    #pragma unroll
    for (int j = 0; j < 4; ++j) {
        int qq = lw * 16 + quad * 4 + j;
        t32[qq * T32STR + g * 32 + col * 2 + 0] = m1[j];
        t32[qq * T32STR + g * 32 + col * 2 + 1] = m2[j];
    }
    __syncthreads();
    {
        int q  = tid & 63;                     // query
        int wt = tid >> 6;                     // worker 0..7, items wt*8..wt*8+7
        float v[8]; int r[8];
        #pragma unroll
        for (int u = 0; u < 8; ++u) { v[u] = t32[q * T32STR + wt * 8 + u]; r[u] = 0; }
        #pragma unroll 8
        for (int jj = 0; jj < 64; ++jj) {
            float vj = t32[q * T32STR + jj];   // odd stride -> 2-way max, no conflicts
            #pragma unroll
            for (int u = 0; u < 8; ++u)
                r[u] += (int)(vj < v[u]) | ((int)(vj == v[u]) & (int)(jj < wt * 8 + u));
        }
        #pragma unroll
        for (int u = 0; u < 8; ++u)
            if (r[u] == KNN - 1) tq[q] = v[u];
        if (tid < QPB) scnt[tid] = 0;
    }
    __syncthreads();
    float T2[4];
    #pragma unroll
    for (int j = 0; j < 4; ++j) T2[j] = tq[lw * 16 + quad * 4 + j] + MARGIN;

    // ================= PASS 2: rescan, atomic survivor append ==========
    stage(0);
    __syncthreads();
    #pragma unroll 1
    for (int I = 0; I < 32; ++I) {
        if (I + 1 < 32) stage(I + 1);
        const char*  cb = bufat(I);
        const float* sv = (const float*)(cb + OFF_SQ);
        int tbase = tileof(I) * TILEC;
        #pragma unroll
        for (int st = 0; st < 8; ++st) {
            half8 bh = *(const half8*)(cb + st * 1024 + lane * 16);
            float sc = sv[st * 16 + col];
            float4v acc = __builtin_amdgcn_mfma_f32_16x16x32_f16(
                qh, bh, (float4v){0.f, 0.f, 0.f, 0.f}, 0, 0, 0);
            #pragma unroll
            for (int j = 0; j < 4; ++j) {
                float key = fmaf(-2.f, acc[j], sc);
                if (key < T2[j]) {
                    int qq = lw * 16 + quad * 4 + j;
                    int slot = atomicAdd(&scnt[qq], 1);
                    if (slot < SCAP)
                        slist[qq * SCAP + slot] = tbase + st * 16 + col;
                }
            }
        }
        __syncthreads();
    }

    // ================= PASS 3: exact fp32 re-check of survivors ==========
    // unroll 2 keeps the live set ~20 regs (no spill at the 64-VGPR budget)
    {
        int qq = tid & 63, sb8 = tid >> 6;     // 8 workers per query
        int n = scnt[qq]; if (n > SCAP) n = SCAP;
        const float4* xi4 = (const float4*)(xb + (size_t)(qbl + qq) * CCH);
        for (int s = sb8; s < n; s += 8) {
            int jdx = slist[qq * SCAP + s];
            const float4* xj = (const float4*)(xb + (size_t)jdx * CCH);
            float a0 = 0.f, a1 = 0.f, a2 = 0.f, a3 = 0.f;
            #pragma unroll 2
            for (int k = 0; k < 8; ++k) {
                float4 cv = xj[k], qv = xi4[k];
                a0 = fmaf(cv.x, qv.x, a0); a1 = fmaf(cv.y, qv.y, a1);
                a2 = fmaf(cv.z, qv.z, a2); a3 = fmaf(cv.w, qv.w, a3);
            }
            float dot = (a0 + a1) + (a2 + a3);
            skeys[qq * SCAP + s] = fmaf(-2.f, dot, sqb[jdx]);
        }
    }
    __syncthreads();
    // ---- exact top-16 set via rank (lex on (key, idx)); kn order = rank.
    // n >= 16 guaranteed (threshold >= true 16th + MARGIN covers fp16 error).
    {
        int q  = tid & 63;
        int wt = tid >> 6;
        int n = scnt[q]; if (n > SCAP) n = SCAP;
        for (int s = wt; s < n; s += 8) {
            float k = skeys[q * SCAP + s];
            int   i = slist[q * SCAP + s];
            int rank = 0;
            #pragma unroll 4
            for (int jj = 0; jj < n; ++jj) {
                float kj = skeys[q * SCAP + jj];   // stride 57 -> conflict-free
                int   ij = slist[q * SCAP + jj];
                rank += (int)(kj < k) | ((int)(kj == k) & (int)(ij < i));
            }
            if (rank < KNN) kn[q * KNN + rank] = i;
        }
    }
    __syncthreads();

    // ================= epilogue: gather + max-pool + MLP ==========
    {
        int q = tid >> 3, part = tid & 7;      // 8 threads/query, one float4 each
        float4 m0 = make_float4(-INF, -INF, -INF, -INF);
        #pragma unroll 4
        for (int k = 0; k < KNN; ++k) {
            int j = kn[q * KNN + k];
            float4 v = *(const float4*)(xb + (size_t)j * CCH + part * 4);
            m0.x = fmaxf(m0.x, v.x); m0.y = fmaxf(m0.y, v.y);
            m0.z = fmaxf(m0.z, v.z); m0.w = fmaxf(m0.w, v.w);
        }
        float* d = pl + q * 33 + part * 4;
        d[0] = m0.x; d[1] = m0.y; d[2] = m0.z; d[3] = m0.w;
    }
    __syncthreads();
    {
        int l = tid & 63, qg2 = tid >> 6;      // 8 query-slices
        #pragma unroll 1
        for (int qq = qg2; qq < QPB; qq += 8) {
            float acc = bl[l];
            #pragma unroll 8
            for (int c = 0; c < CCH; ++c)
                acc = fmaf(pl[qq * 33 + c], Wl[c * LDIM + l], acc);
            hh[qq * 65 + l] = acc;
        }
    }
    __syncthreads();
    {
        int o = tid & 127, qh2 = tid >> 7;     // 4 query-slices
        #pragma unroll 1
        for (int qq = qh2; qq < QPB; qq += 4) {
            float acc = bc[o];
            #pragma unroll 8
            for (int l = 0; l < LDIM; ++l)
                acc = fmaf(hh[qq * 65 + l], Wc[l * ODIM + o], acc);
            out[(size_t)(qb0 + qq) * ODIM + o] = fmaxf(acc, 0.f);
        }
    }
}

extern "C" void kernel_launch(void* const* d_in, const int* in_sizes, int n_in,
                              void* d_out, int out_size, void* d_ws, size_t ws_size,
                              hipStream_t stream) {
    const float* x  = (const float*)d_in[0];
    const float* Wl = (const float*)d_in[1];
    const float* bl = (const float*)d_in[2];
    const float* Wc = (const float*)d_in[3];
    const float* bc = (const float*)d_in[4];
    float* out = (float*)d_out;
    float*    sqf = (float*)d_ws;                       // 32768 fp32 = 128 KB
    _Float16* xh  = (_Float16*)((char*)d_ws + 131072);  // 32768 x 32 fp16 = 2 MB, frag-order
    (void)in_sizes; (void)n_in; (void)out_size; (void)ws_size;

    hipLaunchKernelGGL(prep_kernel, dim3((4 * NPTS) / 256), dim3(256), 0, stream, x, sqf, xh);
    hipLaunchKernelGGL(graph_layer_kernel, dim3(NBLK), dim3(512), 0, stream,
                       x, sqf, xh, Wl, bl, Wc, bc, out);
}

// Round 16
// 235.601 us; speedup vs baseline: 1.7045x; 1.0006x over previous
//
#include <hip/hip_runtime.h>

#define NPTS   8192
#define CCH    32
#define LDIM   64
#define ODIM   128
#define KNN    16
#define QPB    64                  // queries per block (16 per wave = MFMA tile rows)
#define TILEC  128                 // candidates per LDS tile
#define NTIL   (NPTS / TILEC)      // 64
#define NBLK   ((4 * NPTS) / QPB)  // 512 blocks
#define SCAP   57                  // survivor capacity (worst ~40); odd stride -> conflict-free rank reads
#define MARGIN 0.75f               // >= 2*eps bound for fp16 distance error
#define T32STR 65                  // t32 row stride (odd -> conflict-free column reads)

typedef _Float16 half8   __attribute__((ext_vector_type(8)));
typedef float    float4v __attribute__((ext_vector_type(4)));

// CHAMPION (R15: 192us dispatch / 235.7us bench, VGPR 44, FETCH 6.3MB after
// XCD swizzle) -- graph_layer_kernel UNTOUCHED this round.
// R15 post-mortem: swizzle confirmed (FETCH 20.4->6.3MB) but dur ~neutral ->
// stage loads were already hidden. Remaining arithmetic deficit: the
// bench-dispatch gap (43us) vs prep's ideal ~5us. Old prep: 128 blocks (half
// the CUs IDLE), strided row reads, scattered fragment writes. New prep:
// 256 blocks x 256 threads, one 128-pt record each; coalesced load -> LDS
// [128][33] (pad = conflict-free) -> sq with BIT-IDENTICAL expression order
// (selection unchanged) -> coalesced fp16 slot writes (thread t owns slots
// 2t,2t+1 = contiguous 32B). xh bytes + sqg bits identical to old prep.
//
// LDS map (graph_layer):
//  scan:   buf[g][p] @ (g*2+p)*8704, 4 x 8704 = 34816  (8192 xh + 512 sq each)
//          slist @34816 (64*57*4 = 14592) | scnt @49408 (256) | tq @49664 (256)
//          kn @49920 (4096)  -> total 54016
//          t32 overlay @0 (64*65*4 = 16640) after pass-1 (dead before pass-2 staging)
//  pass3:  skeys overlay @0 (14592)   (stage bufs dead)
//  epilog: pl @0 (8448) | hh @8704 (16640)   (kn alive @49920)
#define LDS_BYTES 54016
#define OFF_SQ   8192              // sq row offset inside a stage buffer
#define OFF_SL   34816
#define OFF_SC   49408
#define OFF_TQ   49664
#define OFF_KN   49920
#define OFF_HH   8704

__device__ __forceinline__ void gload_lds16(const void* g, void* l) {
    __builtin_amdgcn_global_load_lds(
        (const __attribute__((address_space(1))) unsigned int*)g,
        (__attribute__((address_space(3))) unsigned int*)l, 16, 0, 0);
}
__device__ __forceinline__ void gload_lds4(const void* g, void* l) {
    __builtin_amdgcn_global_load_lds(
        (const __attribute__((address_space(1))) unsigned int*)g,
        (__attribute__((address_space(3))) unsigned int*)l, 4, 0, 0);
}

// Prep (rewritten): one 128-point record per block, 256 blocks.
//   slot s in [0,512): st=s>>6, q=(s>>4)&3, col=s&15; holds channels
//   [8q,8q+8) of point st*16+col as half8 at rec + s*16  (same bytes as the
//   old layout: half8 idx (p>>7)*512 + ((p>>4)&7)*64 + (p&15), quad stride 16).
__global__ __launch_bounds__(256)
void prep_kernel(const float* __restrict__ x, float* __restrict__ sqg,
                 _Float16* __restrict__ xh) {
    __shared__ float lx[128 * 33];             // [pt][ch], +1 pad -> conflict-free
    const int r = blockIdx.x;                  // record 0..255 (batch b = r>>6)
    const int t = threadIdx.x;
    const float* src = x + (size_t)r * 4096;   // 128 pts x 32 ch, contiguous

    #pragma unroll
    for (int i = 0; i < 4; ++i) {              // coalesced: lane-consecutive 16B
        int f4 = t + i * 256;                  // float4 index 0..1023
        float4 v = ((const float4*)src)[f4];
        int f = f4 * 4, pt = f >> 5, ch = f & 31;
        float* d = lx + pt * 33 + ch;
        d[0] = v.x; d[1] = v.y; d[2] = v.z; d[3] = v.w;
    }
    __syncthreads();
    if (t < 128) {                             // sq: SAME expression tree as before
        const float* row = lx + t * 33;
        float s = 0.f;
        #pragma unroll
        for (int k = 0; k < 8; ++k) {
            float a = row[4*k], b = row[4*k+1], c = row[4*k+2], d = row[4*k+3];
            s += a * a + b * b + c * c + d * d;
        }
        sqg[r * 128 + t] = s;                  // coalesced
    }
    char* rec = (char*)xh + (size_t)r * 8192;
    #pragma unroll
    for (int i = 0; i < 2; ++i) {              // thread t -> slots 2t, 2t+1 (32B contig)
        int s2 = t * 2 + i;
        int st = s2 >> 6, q = (s2 >> 4) & 3, col = s2 & 15;
        const float* row = lx + (st * 16 + col) * 33 + q * 8;
        half8 h;
        #pragma unroll
        for (int j = 0; j < 8; ++j) h[j] = (_Float16)row[j];
        *(half8*)(rec + s2 * 16) = h;          // coalesced
    }
}

__global__ __launch_bounds__(512, 4)
void graph_layer_kernel(const float* __restrict__ x,
                        const float* __restrict__ sqg,
                        const _Float16* __restrict__ xh,
                        const float* __restrict__ Wl,
                        const float* __restrict__ bl,
                        const float* __restrict__ Wc,
                        const float* __restrict__ bc,
                        float* __restrict__ out)
{
    __shared__ __align__(16) char smem[LDS_BYTES];
    int*   slist = (int*)(smem + OFF_SL);
    float* t32   = (float*)smem;               // overlay on stage bufs, post-pass-1
    int*   scnt  = (int*)(smem + OFF_SC);
    float* tq    = (float*)(smem + OFF_TQ);
    float* skeys = (float*)smem;               // pass-3 overlay
    int*   kn    = (int*)(smem + OFF_KN);
    float* pl    = (float*)smem;               // epilogue overlays
    float* hh    = (float*)(smem + OFF_HH);

    const int tid  = threadIdx.x;
    const int lane = tid & 63;
    const int w    = tid >> 6;                 // 0..7
    const int g    = w >> 2;                   // wave group: 0 = even tiles, 1 = odd
    const int lw   = w & 3;                    // wave within group
    const int col  = lane & 15;                // candidate column / A-frag row
    const int quad = lane >> 4;
    const float INF = __builtin_inff();

    // XCD-aware swizzle: dispatch XCD = bid%8 (round-robin). Map so each XCD
    // serves ONE batch -> its L2 holds just that batch's 2.1MB xh. Bijective.
    const int bid = blockIdx.x;
    const int xcd = bid & 7, ixc = bid >> 3;   // ixc in [0,64)
    const int vb  = ((xcd >> 1) << 7) | ((xcd & 1) << 6) | ixc;

    const int qb0 = vb * QPB;
    const int b   = qb0 >> 13;
    const int qbl = qb0 & (NPTS - 1);
    const int S   = vb & 31;                   // tile-order stagger
    const float* xb  = x   + (size_t)(b << 13) * CCH;
    const float* sqb = sqg + (b << 13);
    const char*  xhb = (const char*)xh + (size_t)b * NTIL * 8192;

    // ---- A-fragment from fp16 workspace: A[m=col][k=quad*8+j], queries lw*16+col
    half8 qh;
    {
        int p = qb0 + lw * 16 + col;
        qh = *(const half8*)((const char*)xh
              + (size_t)(p >> 7) * 8192 + ((p >> 4) & 7) * 1024
              + quad * 256 + (p & 15) * 16);
    }

    auto tileof = [&](int I) { return (((I + S) & 31) << 1) | g; };
    auto bufat  = [&](int I) { return smem + (((g << 1) | (I & 1)) * 8704); };

    // async stage of super-iter I's tile for this group: 8KB fp16 + 512B sq
    auto stage = [&](int I) {
        char* sb = bufat(I);
        int tile = tileof(I);
        const char* src = xhb + (size_t)tile * 8192;
        int tg = tid & 255;                     // thread index within group
        gload_lds16(src + tg * 16,        sb + lw * 1024);   // lds = base + lane*16
        gload_lds16(src + 4096 + tg * 16, sb + 4096 + lw * 1024);
        if (lw < 2)
            gload_lds4(sqb + tile * TILEC + lw * 64 + lane, sb + OFF_SQ + lw * 256);
    };

    // ================= PASS 1: branch-free per-lane top-2 per query ==========
    float m1[4] = {INF, INF, INF, INF};
    float m2[4] = {INF, INF, INF, INF};

    stage(0);
    __syncthreads();
    #pragma unroll 1
    for (int I = 0; I < 32; ++I) {
        if (I + 1 < 32) stage(I + 1);
        const char*  cb = bufat(I);
        const float* sv = (const float*)(cb + OFF_SQ);
        #pragma unroll
        for (int st = 0; st < 8; ++st) {
            half8 bh = *(const half8*)(cb + st * 1024 + lane * 16);   // conflict-free
            float sc = sv[st * 16 + col];
            float4v acc = __builtin_amdgcn_mfma_f32_16x16x32_f16(
                qh, bh, (float4v){0.f, 0.f, 0.f, 0.f}, 0, 0, 0);
            #pragma unroll
            for (int j = 0; j < 4; ++j) {
                float key = fmaf(-2.f, acc[j], sc);
                float o1  = m1[j];
                m1[j] = fminf(key, o1);
                // 2nd-smallest of {key, o1, m2} == min(m2, max(key, o1)) given o1<=m2
                m2[j] = __builtin_amdgcn_fmed3f(key, o1, m2[j]);
            }
        }
        __syncthreads();
    }

    // ---- per-query threshold: 16th smallest of the 64-value union ----
    // Rank-based (exact, lex tie-break): rank(i) = #{j : v_j < v_i or (==, j<i)}.
    #pragma unroll
    for (int j = 0; j < 4; ++j) {
        int qq = lw * 16 + quad * 4 + j;
        t32[qq * T32STR + g * 32 + col * 2 + 0] = m1[j];
        t32[qq * T32STR + g * 32 + col * 2 + 1] = m2[j];
    }
    __syncthreads();
    {
        int q  = tid & 63;                     // query
        int wt = tid >> 6;                     // worker 0..7, items wt*8..wt*8+7
        float v[8]; int r[8];
        #pragma unroll
        for (int u = 0; u < 8; ++u) { v[u] = t32[q * T32STR + wt * 8 + u]; r[u] = 0; }
        #pragma unroll 8
        for (int jj = 0; jj < 64; ++jj) {
            float vj = t32[q * T32STR + jj];   // odd stride -> 2-way max, no conflicts
            #pragma unroll
            for (int u = 0; u < 8; ++u)
                r[u] += (int)(vj < v[u]) | ((int)(vj == v[u]) & (int)(jj < wt * 8 + u));
        }
        #pragma unroll
        for (int u = 0; u < 8; ++u)
            if (r[u] == KNN - 1) tq[q] = v[u];
        if (tid < QPB) scnt[tid] = 0;
    }
    __syncthreads();
    float T2[4];
    #pragma unroll
    for (int j = 0; j < 4; ++j) T2[j] = tq[lw * 16 + quad * 4 + j] + MARGIN;

    // ================= PASS 2: rescan, atomic survivor append ==========
    stage(0);
    __syncthreads();
    #pragma unroll 1
    for (int I = 0; I < 32; ++I) {
        if (I + 1 < 32) stage(I + 1);
        const char*  cb = bufat(I);
        const float* sv = (const float*)(cb + OFF_SQ);
        int tbase = tileof(I) * TILEC;
        #pragma unroll
        for (int st = 0; st < 8; ++st) {
            half8 bh = *(const half8*)(cb + st * 1024 + lane * 16);
            float sc = sv[st * 16 + col];
            float4v acc = __builtin_amdgcn_mfma_f32_16x16x32_f16(
                qh, bh, (float4v){0.f, 0.f, 0.f, 0.f}, 0, 0, 0);
            #pragma unroll
            for (int j = 0; j < 4; ++j) {
                float key = fmaf(-2.f, acc[j], sc);
                if (key < T2[j]) {
                    int qq = lw * 16 + quad * 4 + j;
                    int slot = atomicAdd(&scnt[qq], 1);
                    if (slot < SCAP)
                        slist[qq * SCAP + slot] = tbase + st * 16 + col;
                }
            }
        }
        __syncthreads();
    }

    // ================= PASS 3: exact fp32 re-check of survivors ==========
    // unroll 2 keeps the live set ~20 regs (no spill at the 64-VGPR budget)
    {
        int qq = tid & 63, sb8 = tid >> 6;     // 8 workers per query
        int n = scnt[qq]; if (n > SCAP) n = SCAP;
        const float4* xi4 = (const float4*)(xb + (size_t)(qbl + qq) * CCH);
        for (int s = sb8; s < n; s += 8) {
            int jdx = slist[qq * SCAP + s];
            const float4* xj = (const float4*)(xb + (size_t)jdx * CCH);
            float a0 = 0.f, a1 = 0.f, a2 = 0.f, a3 = 0.f;
            #pragma unroll 2
            for (int k = 0; k < 8; ++k) {
                float4 cv = xj[k], qv = xi4[k];
                a0 = fmaf(cv.x, qv.x, a0); a1 = fmaf(cv.y, qv.y, a1);
                a2 = fmaf(cv.z, qv.z, a2); a3 = fmaf(cv.w, qv.w, a3);
            }
            float dot = (a0 + a1) + (a2 + a3);
            skeys[qq * SCAP + s] = fmaf(-2.f, dot, sqb[jdx]);
        }
    }
    __syncthreads();
    // ---- exact top-16 set via rank (lex on (key, idx)); kn order = rank.
    // n >= 16 guaranteed (threshold >= true 16th + MARGIN covers fp16 error).
    {
        int q  = tid & 63;
        int wt = tid >> 6;
        int n = scnt[q]; if (n > SCAP) n = SCAP;
        for (int s = wt; s < n; s += 8) {
            float k = skeys[q * SCAP + s];
            int   i = slist[q * SCAP + s];
            int rank = 0;
            #pragma unroll 4
            for (int jj = 0; jj < n; ++jj) {
                float kj = skeys[q * SCAP + jj];   // stride 57 -> conflict-free
                int   ij = slist[q * SCAP + jj];
                rank += (int)(kj < k) | ((int)(kj == k) & (int)(ij < i));
            }
            if (rank < KNN) kn[q * KNN + rank] = i;
        }
    }
    __syncthreads();

    // ================= epilogue: gather + max-pool + MLP ==========
    {
        int q = tid >> 3, part = tid & 7;      // 8 threads/query, one float4 each
        float4 m0 = make_float4(-INF, -INF, -INF, -INF);
        #pragma unroll 4
        for (int k = 0; k < KNN; ++k) {
            int j = kn[q * KNN + k];
            float4 v = *(const float4*)(xb + (size_t)j * CCH + part * 4);
            m0.x = fmaxf(m0.x, v.x); m0.y = fmaxf(m0.y, v.y);
            m0.z = fmaxf(m0.z, v.z); m0.w = fmaxf(m0.w, v.w);
        }
        float* d = pl + q * 33 + part * 4;
        d[0] = m0.x; d[1] = m0.y; d[2] = m0.z; d[3] = m0.w;
    }
    __syncthreads();
    {
        int l = tid & 63, qg2 = tid >> 6;      // 8 query-slices
        #pragma unroll 1
        for (int qq = qg2; qq < QPB; qq += 8) {
            float acc = bl[l];
            #pragma unroll 8
            for (int c = 0; c < CCH; ++c)
                acc = fmaf(pl[qq * 33 + c], Wl[c * LDIM + l], acc);
            hh[qq * 65 + l] = acc;
        }
    }
    __syncthreads();
    {
        int o = tid & 127, qh2 = tid >> 7;     // 4 query-slices
        #pragma unroll 1
        for (int qq = qh2; qq < QPB; qq += 4) {
            float acc = bc[o];
            #pragma unroll 8
            for (int l = 0; l < LDIM; ++l)
                acc = fmaf(hh[qq * 65 + l], Wc[l * ODIM + o], acc);
            out[(size_t)(qb0 + qq) * ODIM + o] = fmaxf(acc, 0.f);
        }
    }
}

extern "C" void kernel_launch(void* const* d_in, const int* in_sizes, int n_in,
                              void* d_out, int out_size, void* d_ws, size_t ws_size,
                              hipStream_t stream) {
    const float* x  = (const float*)d_in[0];
    const float* Wl = (const float*)d_in[1];
    const float* bl = (const float*)d_in[2];
    const float* Wc = (const float*)d_in[3];
    const float* bc = (const float*)d_in[4];
    float* out = (float*)d_out;
    float*    sqf = (float*)d_ws;                       // 32768 fp32 = 128 KB
    _Float16* xh  = (_Float16*)((char*)d_ws + 131072);  // 32768 x 32 fp16 = 2 MB, frag-order
    (void)in_sizes; (void)n_in; (void)out_size; (void)ws_size;

    hipLaunchKernelGGL(prep_kernel, dim3(256), dim3(256), 0, stream, x, sqf, xh);
    hipLaunchKernelGGL(graph_layer_kernel, dim3(NBLK), dim3(512), 0, stream,
                       x, sqf, xh, Wl, bl, Wc, bc, out);
}

// Round 17
// 234.728 us; speedup vs baseline: 1.7109x; 1.0037x over previous
//
#include <hip/hip_runtime.h>

#define NPTS   8192
#define CCH    32
#define LDIM   64
#define ODIM   128
#define KNN    16
#define QPB    64                  // queries per block (16 per wave = MFMA tile rows)
#define TILEC  128                 // candidates per LDS tile
#define NTIL   (NPTS / TILEC)      // 64
#define NBLK   ((4 * NPTS) / QPB)  // 512 blocks
#define SCAP   57                  // survivor capacity (worst ~40); odd stride -> conflict-free rank reads
#define MARGIN 0.75f               // >= 2*eps bound for fp16 distance error
#define T32STR 65                  // t32 row stride (odd -> conflict-free column reads)

typedef _Float16 half8   __attribute__((ext_vector_type(8)));
typedef float    float4v __attribute__((ext_vector_type(4)));

// CHAMPION (R15/R16: 192-197us dispatch / 235.6us bench) + ONE change:
// depth-2 counted-vmcnt pipeline (T4, m201 pattern) -- the only sync-policy
// cell never tested ON THIS STRUCTURE (R9-R11 tested it on the worse
// chunk-split). Mechanism: champion's __syncthreads drains vmcnt(0) INCLUDING
// the stage(I+1) issued at the top of the same iteration; any un-landed
// residue is paid at every one of 64 barriers. Now: 3 buffers/group, issue
// stage(I+2) each iteration, and wait vmcnt(3) (= the just-issued stage's
// uniform load count) before a raw s_barrier -> stage loads get a FULL
// iteration in flight and are never drained inside the loop.
// Uniform count: sq staging redistributed across all 4 waves (lanes<32), so
// EVERY wave issues exactly 3 VMEM per stage. qh load drained (vmcnt(0))
// before the prologue so counts are exact. sched_barrier(0) after each raw
// barrier (rule 18). Full __syncthreads at pass ends before LDS overlays.
// Wrapped tail stages (I+2 >= 32 re-stages early tiles) keep counts uniform.
//
// LDS map (71424 B -> 2 blocks/CU: 142848 <= 163840):
//  scan:   bufs 3/group @ g*26112 + k*8704, 6 x 8704 = 52224 (8192 xh + 512 sq)
//          slist @52224 (64*57*4 = 14592) | scnt @66816 (256) | tq @67072 (256)
//          kn @67328 (4096) -> total 71424
//          t32 overlay @0 (16640) after pass-1 drain (dead before pass-2 staging)
//  pass3:  skeys overlay @0 (14592)   (stage bufs dead)
//  epilog: pl @0 (8448) | hh @8704 (16640)   (kn alive @67328)
#define LDS_BYTES 71424
#define OFF_SQ   8192              // sq row offset inside a stage buffer
#define OFF_SL   52224
#define OFF_SC   66816
#define OFF_TQ   67072
#define OFF_KN   67328
#define OFF_HH   8704

__device__ __forceinline__ void gload_lds16(const void* g, void* l) {
    __builtin_amdgcn_global_load_lds(
        (const __attribute__((address_space(1))) unsigned int*)g,
        (__attribute__((address_space(3))) unsigned int*)l, 16, 0, 0);
}
__device__ __forceinline__ void gload_lds4(const void* g, void* l) {
    __builtin_amdgcn_global_load_lds(
        (const __attribute__((address_space(1))) unsigned int*)g,
        (__attribute__((address_space(3))) unsigned int*)l, 4, 0, 0);
}

// Prep (R16, verified): one 128-point record per block, 256 blocks; coalesced
// load -> LDS [128][33] -> bit-identical sq -> coalesced fp16 slot writes.
__global__ __launch_bounds__(256)
void prep_kernel(const float* __restrict__ x, float* __restrict__ sqg,
                 _Float16* __restrict__ xh) {
    __shared__ float lx[128 * 33];
    const int r = blockIdx.x;
    const int t = threadIdx.x;
    const float* src = x + (size_t)r * 4096;

    #pragma unroll
    for (int i = 0; i < 4; ++i) {
        int f4 = t + i * 256;
        float4 v = ((const float4*)src)[f4];
        int f = f4 * 4, pt = f >> 5, ch = f & 31;
        float* d = lx + pt * 33 + ch;
        d[0] = v.x; d[1] = v.y; d[2] = v.z; d[3] = v.w;
    }
    __syncthreads();
    if (t < 128) {
        const float* row = lx + t * 33;
        float s = 0.f;
        #pragma unroll
        for (int k = 0; k < 8; ++k) {
            float a = row[4*k], b = row[4*k+1], c = row[4*k+2], d = row[4*k+3];
            s += a * a + b * b + c * c + d * d;
        }
        sqg[r * 128 + t] = s;
    }
    char* rec = (char*)xh + (size_t)r * 8192;
    #pragma unroll
    for (int i = 0; i < 2; ++i) {
        int s2 = t * 2 + i;
        int st = s2 >> 6, q = (s2 >> 4) & 3, col = s2 & 15;
        const float* row = lx + (st * 16 + col) * 33 + q * 8;
        half8 h;
        #pragma unroll
        for (int j = 0; j < 8; ++j) h[j] = (_Float16)row[j];
        *(half8*)(rec + s2 * 16) = h;
    }
}

__global__ __launch_bounds__(512, 4)
void graph_layer_kernel(const float* __restrict__ x,
                        const float* __restrict__ sqg,
                        const _Float16* __restrict__ xh,
                        const float* __restrict__ Wl,
                        const float* __restrict__ bl,
                        const float* __restrict__ Wc,
                        const float* __restrict__ bc,
                        float* __restrict__ out)
{
    __shared__ __align__(16) char smem[LDS_BYTES];
    int*   slist = (int*)(smem + OFF_SL);
    float* t32   = (float*)smem;               // overlay on stage bufs, post-pass-1
    int*   scnt  = (int*)(smem + OFF_SC);
    float* tq    = (float*)(smem + OFF_TQ);
    float* skeys = (float*)smem;               // pass-3 overlay
    int*   kn    = (int*)(smem + OFF_KN);
    float* pl    = (float*)smem;               // epilogue overlays
    float* hh    = (float*)(smem + OFF_HH);

    const int tid  = threadIdx.x;
    const int lane = tid & 63;
    const int w    = tid >> 6;                 // 0..7
    const int g    = w >> 2;                   // wave group: 0 = even tiles, 1 = odd
    const int lw   = w & 3;                    // wave within group
    const int col  = lane & 15;                // candidate column / A-frag row
    const int quad = lane >> 4;
    const float INF = __builtin_inff();

    // XCD-aware swizzle (R15-verified: FETCH 20.4->6.3MB). Bijective on [0,512).
    const int bid = blockIdx.x;
    const int xcd = bid & 7, ixc = bid >> 3;
    const int vb  = ((xcd >> 1) << 7) | ((xcd & 1) << 6) | ixc;

    const int qb0 = vb * QPB;
    const int b   = qb0 >> 13;
    const int qbl = qb0 & (NPTS - 1);
    const int S   = vb & 31;                   // tile-order stagger
    const float* xb  = x   + (size_t)(b << 13) * CCH;
    const float* sqb = sqg + (b << 13);
    const char*  xhb = (const char*)xh + (size_t)b * NTIL * 8192;

    // ---- A-fragment from fp16 workspace: A[m=col][k=quad*8+j], queries lw*16+col
    half8 qh;
    {
        int p = qb0 + lw * 16 + col;
        qh = *(const half8*)((const char*)xh
              + (size_t)(p >> 7) * 8192 + ((p >> 4) & 7) * 1024
              + quad * 256 + (p & 15) * 16);
    }
    asm volatile("s_waitcnt vmcnt(0)" ::: "memory");   // exact vmcnt counts from here

    auto tileof = [&](int I) { return (((I + S) & 31) << 1) | g; };

    // stage: EXACTLY 3 VMEM per wave (2x gload16 frag + 1x gload4 sq, lanes<32)
    auto stage_to = [&](char* sb, int I) {
        int tile = tileof(I);
        const char* src = xhb + (size_t)tile * 8192;
        int tg = tid & 255;                     // thread index within group
        gload_lds16(src + tg * 16,        sb + lw * 1024);   // lds = base + lane*16
        gload_lds16(src + 4096 + tg * 16, sb + 4096 + lw * 1024);
        if (lane < 32)                          // all 4 waves: 32 lanes x 4B = 128B each
            gload_lds4(sqb + tile * TILEC + lw * 32 + lane, sb + OFF_SQ + lw * 128);
    };

    // ================= PASS 1: branch-free per-lane top-2 per query ==========
    float m1[4] = {INF, INF, INF, INF};
    float m2[4] = {INF, INF, INF, INF};

    {
        char* base = smem + g * 26112;
        char *p0 = base, *p1 = base + 8704, *p2 = base + 17408;
        stage_to(p0, 0); stage_to(p1, 1);
        asm volatile("s_waitcnt vmcnt(3)" ::: "memory");   // retire stage(0), keep stage(1)
        __builtin_amdgcn_s_barrier();
        __builtin_amdgcn_sched_barrier(0);
        #pragma unroll 1
        for (int I = 0; I < 32; ++I) {
            stage_to(p2, I + 2);               // wrapped at tail: harmless restage
            const float* sv = (const float*)(p0 + OFF_SQ);
            #pragma unroll
            for (int st = 0; st < 8; ++st) {
                half8 bh = *(const half8*)(p0 + st * 1024 + lane * 16);  // conflict-free
                float sc = sv[st * 16 + col];
                float4v acc = __builtin_amdgcn_mfma_f32_16x16x32_f16(
                    qh, bh, (float4v){0.f, 0.f, 0.f, 0.f}, 0, 0, 0);
                #pragma unroll
                for (int j = 0; j < 4; ++j) {
                    float key = fmaf(-2.f, acc[j], sc);
                    float o1  = m1[j];
                    m1[j] = fminf(key, o1);
                    // 2nd-smallest of {key,o1,m2} == min(m2, max(key,o1)) given o1<=m2
                    m2[j] = __builtin_amdgcn_fmed3f(key, o1, m2[j]);
                }
            }
            asm volatile("s_waitcnt vmcnt(3)" ::: "memory");  // retire stage(I+1), keep I+2
            __builtin_amdgcn_s_barrier();
            __builtin_amdgcn_sched_barrier(0);
            char* t_ = p0; p0 = p1; p1 = p2; p2 = t_;
        }
    }
    __syncthreads();   // full drain (wrapped stages in flight) before t32 overlay

    // ---- per-query threshold: 16th smallest of the 64-value union ----
    // Rank-based (exact, lex tie-break): rank(i) = #{j : v_j < v_i or (==, j<i)}.
    #pragma unroll
    for (int j = 0; j < 4; ++j) {
        int qq = lw * 16 + quad * 4 + j;
        t32[qq * T32STR + g * 32 + col * 2 + 0] = m1[j];
        t32[qq * T32STR + g * 32 + col * 2 + 1] = m2[j];
    }
    __syncthreads();
    {
        int q  = tid & 63;                     // query
        int wt = tid >> 6;                     // worker 0..7, items wt*8..wt*8+7
        float v[8]; int r[8];
        #pragma unroll
        for (int u = 0; u < 8; ++u) { v[u] = t32[q * T32STR + wt * 8 + u]; r[u] = 0; }
        #pragma unroll 8
        for (int jj = 0; jj < 64; ++jj) {
            float vj = t32[q * T32STR + jj];   // odd stride -> 2-way max, no conflicts
            #pragma unroll
            for (int u = 0; u < 8; ++u)
                r[u] += (int)(vj < v[u]) | ((int)(vj == v[u]) & (int)(jj < wt * 8 + u));
        }
        #pragma unroll
        for (int u = 0; u < 8; ++u)
            if (r[u] == KNN - 1) tq[q] = v[u];
        if (tid < QPB) scnt[tid] = 0;
    }
    __syncthreads();
    float T2[4];
    #pragma unroll
    for (int j = 0; j < 4; ++j) T2[j] = tq[lw * 16 + quad * 4 + j] + MARGIN;

    // ================= PASS 2: rescan, atomic survivor append ==========
    {
        char* base = smem + g * 26112;
        char *p0 = base, *p1 = base + 8704, *p2 = base + 17408;
        stage_to(p0, 0); stage_to(p1, 1);
        asm volatile("s_waitcnt vmcnt(3)" ::: "memory");
        __builtin_amdgcn_s_barrier();
        __builtin_amdgcn_sched_barrier(0);
        #pragma unroll 1
        for (int I = 0; I < 32; ++I) {
            stage_to(p2, I + 2);
            const float* sv = (const float*)(p0 + OFF_SQ);
            int tbase = tileof(I) * TILEC;
            #pragma unroll
            for (int st = 0; st < 8; ++st) {
                half8 bh = *(const half8*)(p0 + st * 1024 + lane * 16);
                float sc = sv[st * 16 + col];
                float4v acc = __builtin_amdgcn_mfma_f32_16x16x32_f16(
                    qh, bh, (float4v){0.f, 0.f, 0.f, 0.f}, 0, 0, 0);
                #pragma unroll
                for (int j = 0; j < 4; ++j) {
                    float key = fmaf(-2.f, acc[j], sc);
                    if (key < T2[j]) {
                        int qq = lw * 16 + quad * 4 + j;
                        int slot = atomicAdd(&scnt[qq], 1);
                        if (slot < SCAP)
                            slist[qq * SCAP + slot] = tbase + st * 16 + col;
                    }
                }
            }
            asm volatile("s_waitcnt vmcnt(3)" ::: "memory");
            __builtin_amdgcn_s_barrier();
            __builtin_amdgcn_sched_barrier(0);
            char* t_ = p0; p0 = p1; p1 = p2; p2 = t_;
        }
    }
    __syncthreads();   // full drain before skeys overlay

    // ================= PASS 3: exact fp32 re-check of survivors ==========
    {
        int qq = tid & 63, sb8 = tid >> 6;     // 8 workers per query
        int n = scnt[qq]; if (n > SCAP) n = SCAP;
        const float4* xi4 = (const float4*)(xb + (size_t)(qbl + qq) * CCH);
        for (int s = sb8; s < n; s += 8) {
            int jdx = slist[qq * SCAP + s];
            const float4* xj = (const float4*)(xb + (size_t)jdx * CCH);
            float a0 = 0.f, a1 = 0.f, a2 = 0.f, a3 = 0.f;
            #pragma unroll 2
            for (int k = 0; k < 8; ++k) {
                float4 cv = xj[k], qv = xi4[k];
                a0 = fmaf(cv.x, qv.x, a0); a1 = fmaf(cv.y, qv.y, a1);
                a2 = fmaf(cv.z, qv.z, a2); a3 = fmaf(cv.w, qv.w, a3);
            }
            float dot = (a0 + a1) + (a2 + a3);
            skeys[qq * SCAP + s] = fmaf(-2.f, dot, sqb[jdx]);
        }
    }
    __syncthreads();
    // ---- exact top-16 set via rank (lex on (key, idx)); kn order = rank.
    // n >= 16 guaranteed (threshold >= true 16th + MARGIN covers fp16 error).
    {
        int q  = tid & 63;
        int wt = tid >> 6;
        int n = scnt[q]; if (n > SCAP) n = SCAP;
        for (int s = wt; s < n; s += 8) {
            float k = skeys[q * SCAP + s];
            int   i = slist[q * SCAP + s];
            int rank = 0;
            #pragma unroll 4
            for (int jj = 0; jj < n; ++jj) {
                float kj = skeys[q * SCAP + jj];   // stride 57 -> conflict-free
                int   ij = slist[q * SCAP + jj];
                rank += (int)(kj < k) | ((int)(kj == k) & (int)(ij < i));
            }
            if (rank < KNN) kn[q * KNN + rank] = i;
        }
    }
    __syncthreads();

    // ================= epilogue: gather + max-pool + MLP ==========
    {
        int q = tid >> 3, part = tid & 7;      // 8 threads/query, one float4 each
        float4 m0 = make_float4(-INF, -INF, -INF, -INF);
        #pragma unroll 4
        for (int k = 0; k < KNN; ++k) {
            int j = kn[q * KNN + k];
            float4 v = *(const float4*)(xb + (size_t)j * CCH + part * 4);
            m0.x = fmaxf(m0.x, v.x); m0.y = fmaxf(m0.y, v.y);
            m0.z = fmaxf(m0.z, v.z); m0.w = fmaxf(m0.w, v.w);
        }
        float* d = pl + q * 33 + part * 4;
        d[0] = m0.x; d[1] = m0.y; d[2] = m0.z; d[3] = m0.w;
    }
    __syncthreads();
    {
        int l = tid & 63, qg2 = tid >> 6;      // 8 query-slices
        #pragma unroll 1
        for (int qq = qg2; qq < QPB; qq += 8) {
            float acc = bl[l];
            #pragma unroll 8
            for (int c = 0; c < CCH; ++c)
                acc = fmaf(pl[qq * 33 + c], Wl[c * LDIM + l], acc);
            hh[qq * 65 + l] = acc;
        }
    }
    __syncthreads();
    {
        int o = tid & 127, qh2 = tid >> 7;     // 4 query-slices
        #pragma unroll 1
        for (int qq = qh2; qq < QPB; qq += 4) {
            float acc = bc[o];
            #pragma unroll 8
            for (int l = 0; l < LDIM; ++l)
                acc = fmaf(hh[qq * 65 + l], Wc[l * ODIM + o], acc);
            out[(size_t)(qb0 + qq) * ODIM + o] = fmaxf(acc, 0.f);
        }
    }
}

extern "C" void kernel_launch(void* const* d_in, const int* in_sizes, int n_in,
                              void* d_out, int out_size, void* d_ws, size_t ws_size,
                              hipStream_t stream) {
    const float* x  = (const float*)d_in[0];
    const float* Wl = (const float*)d_in[1];
    const float* bl = (const float*)d_in[2];
    const float* Wc = (const float*)d_in[3];
    const float* bc = (const float*)d_in[4];
    float* out = (float*)d_out;
    float*    sqf = (float*)d_ws;                       // 32768 fp32 = 128 KB
    _Float16* xh  = (_Float16*)((char*)d_ws + 131072);  // 32768 x 32 fp16 = 2 MB, frag-order
    (void)in_sizes; (void)n_in; (void)out_size; (void)ws_size;

    hipLaunchKernelGGL(prep_kernel, dim3(256), dim3(256), 0, stream, x, sqf, xh);
    hipLaunchKernelGGL(graph_layer_kernel, dim3(NBLK), dim3(512), 0, stream,
                       x, sqf, xh, Wl, bl, Wc, bc, out);
}